// Round 1
// baseline (151.792 us; speedup 1.0000x reference)
//
#include <hip/hip_runtime.h>
#include <math.h>

#define NN 4096
#define DD 127
#define HH 128
#define OUTD 3
#define NTYPES 6
#define SIM_THRESH 0.9f
#define BN_EPS 1e-5f
#define MROW 4    // rows per block in maskgather
#define NREP 8    // accumulator replicas
// Full-row cross-type neighbor cap: Binomial(3413, 0.05): mean 171, sigma 12.7
// -> 384 = 16.7-sigma bound.
#define LMAX 384
// Half-row list capacity for gather2 (mean 85, sigma 9 -> 19 sigma).
#define LMAXH 256

typedef unsigned short ushortT;
typedef __attribute__((ext_vector_type(8))) short short8;   // 8 bf16 (4 VGPRs)
typedef __attribute__((ext_vector_type(4))) float f32x4;

// round-to-nearest-even fp32 -> bf16 (bit pattern)
static __device__ inline ushortT f2bf(float f) {
    unsigned u = __float_as_uint(f);
    unsigned r = (u + 0x7fffu + ((u >> 16) & 1u)) >> 16;
    return (ushortT)r;
}
static __device__ inline float bflo(unsigned w) { return __uint_as_float(w << 16); }
static __device__ inline float bfhi(unsigned w) { return __uint_as_float(w & 0xffff0000u); }

#define BFACC(vv)                                                         \
    {                                                                     \
        acc[0] += __uint_as_float((vv).x << 16);                          \
        acc[1] += __uint_as_float((vv).x & 0xffff0000u);                  \
        acc[2] += __uint_as_float((vv).y << 16);                          \
        acc[3] += __uint_as_float((vv).y & 0xffff0000u);                  \
        acc[4] += __uint_as_float((vv).z << 16);                          \
        acc[5] += __uint_as_float((vv).z & 0xffff0000u);                  \
        acc[6] += __uint_as_float((vv).w << 16);                          \
        acc[7] += __uint_as_float((vv).w & 0xffff0000u);                  \
    }

// ---------------------------------------------------------------------------
// Kernel P: blocks 0..7 convert W to bf16 (row-major). Blocks 8..263: 16-row
// strips: xbf (bf16 only — fp32 x dropped, strip staged in LDS for the S0
// sums), fn, histogram, S0 type-sums (NREP replicas).
// ---------------------------------------------------------------------------
__global__ __launch_bounds__(256) void prep(
    const float* __restrict__ x_now, const int* __restrict__ sat,
    const float* __restrict__ Wl, const float* __restrict__ Wr,
    ushortT* __restrict__ Wbf, ushortT* __restrict__ xbf,
    float4* __restrict__ fn, int* __restrict__ cnt, float* __restrict__ S0rep)
{
    int t = threadIdx.x;
    if (blockIdx.x < 8) {
        int baseidx = blockIdx.x * 8192;
        #pragma unroll
        for (int it = 0; it < 32; ++it) {
            int idx = baseidx + it * 256 + t;
            float v = (idx < 32768) ? Wl[idx] : Wr[idx - 32768];
            Wbf[idx] = f2bf(v);
        }
        return;
    }

    int sb = blockIdx.x - 8;           // strip 0..255
    int base = sb * 16;
    int rep = sb & (NREP - 1);
    __shared__ int stypes[16];
    __shared__ float xs[16][HH];       // 8 KB strip stage
    int myti = -1;
    if (t < 16) {
        int row = base + t;
        int ti = sat[row]; ti = min(max(ti, 0), NTYPES - 1);
        stypes[t] = ti; myti = ti;
        const float* rp = x_now + (size_t)row * DD;
        float f0 = rp[0], f2 = rp[1], f3 = rp[2];
        float nrm = fmaxf(sqrtf(2.f * f0 * f0 + f2 * f2 + f3 * f3), 1e-12f);
        float inv = 1.f / nrm;
        fn[row] = make_float4(f0 * inv, f0 * inv, f2 * inv, f3 * inv);
    }
    #pragma unroll
    for (int it = 0; it < 8; ++it) {
        int lin = it * 256 + t;        // 0..2047
        int rl = lin >> 7, col = lin & 127;
        int row = base + rl;
        const float* rp = x_now + (size_t)row * DD;
        float v = (col == 0) ? rp[0] : rp[col - 1];
        xs[rl][col] = v;
        xbf[(size_t)row * HH + col] = f2bf(v);
    }
    __syncthreads();
    if (t < 64) {
        #pragma unroll
        for (int tt = 0; tt < NTYPES; ++tt) {
            unsigned long long m = __ballot(myti == tt);
            if (t == 0) {
                int c = __popcll(m);
                if (c) atomicAdd(&cnt[rep * NTYPES + tt], c);
            }
        }
    }
    if (t < 128) {
        float acc[NTYPES] = {0.f, 0.f, 0.f, 0.f, 0.f, 0.f};
        for (int r = 0; r < 16; ++r) {
            float v = xs[r][t];
            int tt = stypes[r];
            #pragma unroll
            for (int q = 0; q < NTYPES; ++q) acc[q] += (tt == q) ? v : 0.f;
        }
        #pragma unroll
        for (int q = 0; q < NTYPES; ++q)
            atomicAdd(&S0rep[(rep * NTYPES + q) * HH + t], acc[q]);
    }
}

// ---------------------------------------------------------------------------
// Kernel MG (fused build_mask + layer-1 gather): per block 4 rows.
// Phase 1: bitmask + degree (as before), full words kept in LDS.
// Phase 2: one wave per row decodes its 128 words, gathers the bf16 cross-
// type neighbors, adds S0 type-sum minus self, writes mbf. No mask re-read,
// no fp32 self-row (bf16 self: error ~ulp/deg ~1e-5).
// ---------------------------------------------------------------------------
__global__ __launch_bounds__(256) void maskgather(
    const float4* __restrict__ fn, const int* __restrict__ sat,
    const int* __restrict__ cnt, const float* __restrict__ S,
    const ushortT* __restrict__ hbf, unsigned* __restrict__ mask,
    float* __restrict__ deg, ushortT* __restrict__ mbf)
{
    int i0 = blockIdx.x * MROW;
    int t = threadIdx.x;
    int w = t & 127;
    int half = t >> 7;

    __shared__ unsigned wbuf[MROW][HH];      // 2 KB: partial then full words
    __shared__ ushortT list[MROW][LMAX];     // 3 KB
    __shared__ float sdeg[MROW];
    __shared__ int stypes[MROW];
    __shared__ int wt[2][MROW];

    float4 fi[MROW];
    int ti[MROW];
    #pragma unroll
    for (int r = 0; r < MROW; ++r) {
        fi[r] = fn[i0 + r];
        int tt = sat[i0 + r];
        ti[r] = min(max(tt, 0), NTYPES - 1);
    }
    unsigned word[MROW] = {0, 0, 0, 0};
    int bbase = half * 16;
    for (int bb = 0; bb < 16; ++bb) {
        int b = bbase + bb;
        int j = b * 128 + w;
        float4 fj = fn[j];
        int tj = sat[j];
        #pragma unroll
        for (int r = 0; r < MROW; ++r) {
            float dot = fi[r].x * fj.x + fi[r].y * fj.y
                      + fi[r].z * fj.z + fi[r].w * fj.w;
            if (tj != ti[r] && dot > SIM_THRESH) word[r] |= (1u << b);
        }
    }
    if (half == 1) {
        #pragma unroll
        for (int r = 0; r < MROW; ++r) wbuf[r][w] = word[r];
    }
    __syncthreads();
    if (half == 0) {
        int pcs[MROW];
        #pragma unroll
        for (int r = 0; r < MROW; ++r) {
            unsigned full = word[r] | wbuf[r][w];
            wbuf[r][w] = full;                       // full word back to LDS
            mask[(size_t)(i0 + r) * 128 + w] = full; // for layer-2 gather
            pcs[r] = __popc(full);
        }
        int lane = w & 63, wv2 = w >> 6;
        for (int s = 32; s; s >>= 1) {
            #pragma unroll
            for (int r = 0; r < MROW; ++r) pcs[r] += __shfl_down(pcs[r], s);
        }
        if (lane == 0) {
            #pragma unroll
            for (int r = 0; r < MROW; ++r) wt[wv2][r] = pcs[r];
        }
    }
    __syncthreads();
    if (t < MROW) {
        int r = t;
        int ctot = 0;
        #pragma unroll
        for (int rr = 0; rr < NREP; ++rr) ctot += cnt[rr * NTYPES + ti[r]];
        float d = (float)(ctot - 1 + wt[0][r] + wt[1][r]);
        d = fmaxf(d, 1.0f);
        sdeg[r] = d;
        deg[i0 + r] = d;
        stypes[r] = ti[r];
    }
    __syncthreads();

    // ---- phase 2: wave wv owns row i0+wv ----
    int wv = t >> 6, lane = t & 63;
    int i = i0 + wv;
    unsigned w0 = wbuf[wv][lane];
    unsigned w1 = wbuf[wv][lane + 64];
    int pc0 = __popc(w0), pc1 = __popc(w1);
    int x = pc0 + pc1;
    for (int s = 1; s < 64; s <<= 1) {
        int v = __shfl_up(x, s);
        if (lane >= s) x += v;
    }
    int ncnt = __shfl(x, 63);
    int ofs = x - pc0 - pc1;
    unsigned ww = w0;
    while (ww) {
        int b = __ffs(ww) - 1; ww &= ww - 1;
        list[wv][ofs++] = (ushortT)(b * 128 + lane);
    }
    ww = w1;
    while (ww) {
        int b = __ffs(ww) - 1; ww &= ww - 1;
        list[wv][ofs++] = (ushortT)(b * 128 + lane + 64);
    }
    // list[wv] written and read by the same wave — no barrier needed.

    int q = lane >> 4;        // neighbor slot 0..3
    int c = lane & 15;        // column chunk (8 bf16)
    const uint4* __restrict__ hb4 = (const uint4*)hbf;
    float acc[8] = {0.f, 0.f, 0.f, 0.f, 0.f, 0.f, 0.f, 0.f};
    int g = 0;
    for (; g + 24 <= ncnt; g += 24) {
        int j0 = list[wv][g + q];
        int j1 = list[wv][g + 4 + q];
        int j2 = list[wv][g + 8 + q];
        int j3 = list[wv][g + 12 + q];
        int j4 = list[wv][g + 16 + q];
        int j5 = list[wv][g + 20 + q];
        uint4 v0 = hb4[j0 * 16 + c];
        uint4 v1 = hb4[j1 * 16 + c];
        uint4 v2 = hb4[j2 * 16 + c];
        uint4 v3 = hb4[j3 * 16 + c];
        uint4 v4 = hb4[j4 * 16 + c];
        uint4 v5 = hb4[j5 * 16 + c];
        BFACC(v0); BFACC(v1); BFACC(v2); BFACC(v3); BFACC(v4); BFACC(v5);
    }
    for (; g + 4 <= ncnt; g += 4) {
        int j0 = list[wv][g + q];
        uint4 v0 = hb4[j0 * 16 + c];
        BFACC(v0);
    }
    if (q < ncnt - g) {
        int j0 = list[wv][g + q];
        uint4 v0 = hb4[j0 * 16 + c];
        BFACC(v0);
    }
    #pragma unroll
    for (int d = 0; d < 8; ++d) {
        acc[d] += __shfl_down(acc[d], 32);
        acc[d] += __shfl_down(acc[d], 16);
    }
    if (lane < 16) {
        int tti = stypes[wv];
        float rdeg = 1.f / sdeg[wv];
        float4 Sv0 = {0.f, 0.f, 0.f, 0.f}, Sv1 = {0.f, 0.f, 0.f, 0.f};
        #pragma unroll
        for (int rr = 0; rr < NREP; ++rr) {
            float4 a = ((const float4*)S)[(rr * NTYPES + tti) * 32 + c * 2];
            float4 b = ((const float4*)S)[(rr * NTYPES + tti) * 32 + c * 2 + 1];
            Sv0.x += a.x; Sv0.y += a.y; Sv0.z += a.z; Sv0.w += a.w;
            Sv1.x += b.x; Sv1.y += b.y; Sv1.z += b.z; Sv1.w += b.w;
        }
        uint4 hw = ((const uint4*)(hbf + (size_t)i * HH))[c];
        float m0 = (Sv0.x - bflo(hw.x) + acc[0]) * rdeg;
        float m1 = (Sv0.y - bfhi(hw.x) + acc[1]) * rdeg;
        float m2 = (Sv0.z - bflo(hw.y) + acc[2]) * rdeg;
        float m3 = (Sv0.w - bfhi(hw.y) + acc[3]) * rdeg;
        float m4 = (Sv1.x - bflo(hw.z) + acc[4]) * rdeg;
        float m5 = (Sv1.y - bfhi(hw.z) + acc[5]) * rdeg;
        float m6 = (Sv1.z - bflo(hw.w) + acc[6]) * rdeg;
        float m7 = (Sv1.w - bfhi(hw.w) + acc[7]) * rdeg;
        ushort4 a4, b4;
        a4.x = f2bf(m0); a4.y = f2bf(m1); a4.z = f2bf(m2); a4.w = f2bf(m3);
        b4.x = f2bf(m4); b4.y = f2bf(m5); b4.z = f2bf(m6); b4.w = f2bf(m7);
        ((ushort4*)(mbf + (size_t)i * HH))[c * 2] = a4;
        ((ushort4*)(mbf + (size_t)i * HH))[c * 2 + 1] = b4;
    }
}

// ---------------------------------------------------------------------------
// Kernel G2 (layer-2 gather): as before, but the fp32 self-row is gone —
// self term read from bf16 h1 directly in the epilogue.
// ---------------------------------------------------------------------------
__global__ __launch_bounds__(256, 8) void gather2(
    const ushortT* __restrict__ hbf, const unsigned* __restrict__ mask,
    const float* __restrict__ deg, const float* __restrict__ S,
    const int* __restrict__ sat, ushortT* __restrict__ mbf)
{
    int t = threadIdx.x;
    int wv = t >> 6;
    int lane = t & 63;
    int r  = wv >> 1;
    int hf = wv & 1;
    int i0 = blockIdx.x * 2;
    int i = i0 + r;

    __shared__ ushortT list[4][LMAXH];                   // 2 KB
    __shared__ __align__(16) float part[4][HH];          // 2 KB
    __shared__ int tarr[2];

    if (t < 2) {
        int tt = sat[i0 + t];
        tarr[t] = min(max(tt, 0), NTYPES - 1);
    }

    int widx = hf * 64 + lane;
    unsigned word = mask[(size_t)i * 128 + widx];
    int pc = __popc(word);
    int x = pc;
    for (int s = 1; s < 64; s <<= 1) {
        int v = __shfl_up(x, s);
        if (lane >= s) x += v;
    }
    int ncnt = __shfl(x, 63);
    int ofs = x - pc;
    unsigned ww = word;
    while (ww) {
        int b = __ffs(ww) - 1; ww &= ww - 1;
        list[wv][ofs++] = (ushortT)(b * 128 + widx);
    }

    int q = lane >> 4;
    int c = lane & 15;
    const uint4* __restrict__ hb4 = (const uint4*)hbf;
    float acc[8] = {0.f, 0.f, 0.f, 0.f, 0.f, 0.f, 0.f, 0.f};
    int g = 0;
    for (; g + 24 <= ncnt; g += 24) {
        int j0 = list[wv][g + q];
        int j1 = list[wv][g + 4 + q];
        int j2 = list[wv][g + 8 + q];
        int j3 = list[wv][g + 12 + q];
        int j4 = list[wv][g + 16 + q];
        int j5 = list[wv][g + 20 + q];
        uint4 v0 = hb4[j0 * 16 + c];
        uint4 v1 = hb4[j1 * 16 + c];
        uint4 v2 = hb4[j2 * 16 + c];
        uint4 v3 = hb4[j3 * 16 + c];
        uint4 v4 = hb4[j4 * 16 + c];
        uint4 v5 = hb4[j5 * 16 + c];
        BFACC(v0); BFACC(v1); BFACC(v2); BFACC(v3); BFACC(v4); BFACC(v5);
    }
    for (; g + 4 <= ncnt; g += 4) {
        int j0 = list[wv][g + q];
        uint4 v0 = hb4[j0 * 16 + c];
        BFACC(v0);
    }
    if (q < ncnt - g) {
        int j0 = list[wv][g + q];
        uint4 v0 = hb4[j0 * 16 + c];
        BFACC(v0);
    }
    #pragma unroll
    for (int d = 0; d < 8; ++d) {
        acc[d] += __shfl_down(acc[d], 32);
        acc[d] += __shfl_down(acc[d], 16);
    }
    if (lane < 16) {
        float4 p0 = {acc[0], acc[1], acc[2], acc[3]};
        float4 p1 = {acc[4], acc[5], acc[6], acc[7]};
        ((float4*)part[wv])[c * 2] = p0;
        ((float4*)part[wv])[c * 2 + 1] = p1;
    }
    __syncthreads();

    if (hf == 0 && lane < 32) {
        int cc = lane;
        float4 p0 = ((const float4*)part[wv])[cc];
        float4 p1 = ((const float4*)part[wv + 1])[cc];
        int ti = tarr[r];
        float rdeg = 1.f / deg[i];
        uint2 hw = ((const uint2*)(hbf + (size_t)i * HH))[cc];
        float4 hv = {bflo(hw.x), bfhi(hw.x), bflo(hw.y), bfhi(hw.y)};
        float4 Sv = {0.f, 0.f, 0.f, 0.f};
        #pragma unroll
        for (int rr = 0; rr < NREP; ++rr) {
            float4 sv = ((const float4*)S)[(rr * NTYPES + ti) * 32 + cc];
            Sv.x += sv.x; Sv.y += sv.y; Sv.z += sv.z; Sv.w += sv.w;
        }
        float4 m;
        m.x = (Sv.x - hv.x + p0.x + p1.x) * rdeg;
        m.y = (Sv.y - hv.y + p0.y + p1.y) * rdeg;
        m.z = (Sv.z - hv.z + p0.z + p1.z) * rdeg;
        m.w = (Sv.w - hv.w + p0.w + p1.w) * rdeg;
        ushort4 mb;
        mb.x = f2bf(m.x); mb.y = f2bf(m.y);
        mb.z = f2bf(m.z); mb.w = f2bf(m.w);
        ((ushort4*)(mbf + (size_t)i * HH))[cc] = mb;
    }
}

// ---------------------------------------------------------------------------
// Kernel M1 (layer-1 MFMA GEMM): h1 = relu([mbf | xbf] @ [Wl0 | Wr0]^T + bl0).
// Writes bf16 h1 only (fp32 dropped) + next-layer type sums.
// ---------------------------------------------------------------------------
__global__ __launch_bounds__(256) void gemm_l1(
    const ushortT* __restrict__ mbf, const ushortT* __restrict__ hbf,
    const ushortT* __restrict__ Wlbf, const ushortT* __restrict__ Wrbf,
    const float* __restrict__ bl, const int* __restrict__ sat,
    ushortT* __restrict__ houtbf, float* __restrict__ acc0)
{
    int t = threadIdx.x;
    int wv = t >> 6, lane = t & 63;
    int p = lane & 15, q = lane >> 4;
    int i0 = blockIdx.x * 16;

    __shared__ float sh[16][129];
    __shared__ int stypes[16];
    if (t < 16) {
        int tt = sat[i0 + t];
        stypes[t] = min(max(tt, 0), NTYPES - 1);
    }

    const ushortT* arow_m = mbf + (size_t)(i0 + p) * HH + q * 8;
    const ushortT* arow_h = hbf + (size_t)(i0 + p) * HH + q * 8;
    short8 am[4], ah[4];
    #pragma unroll
    for (int s = 0; s < 4; ++s) {
        am[s] = *(const short8*)(arow_m + s * 32);
        ah[s] = *(const short8*)(arow_h + s * 32);
    }

    #pragma unroll
    for (int nt = 0; nt < 2; ++nt) {
        int n0 = (wv * 2 + nt) * 16;
        const ushortT* brow_l = Wlbf + (size_t)(n0 + p) * HH + q * 8;
        const ushortT* brow_r = Wrbf + (size_t)(n0 + p) * HH + q * 8;
        f32x4 acc = {0.f, 0.f, 0.f, 0.f};
        #pragma unroll
        for (int s = 0; s < 4; ++s) {
            short8 b = *(const short8*)(brow_l + s * 32);
            acc = __builtin_amdgcn_mfma_f32_16x16x32_bf16(am[s], b, acc, 0, 0, 0);
        }
        #pragma unroll
        for (int s = 0; s < 4; ++s) {
            short8 b = *(const short8*)(brow_r + s * 32);
            acc = __builtin_amdgcn_mfma_f32_16x16x32_bf16(ah[s], b, acc, 0, 0, 0);
        }
        int o = n0 + p;
        float bv = bl[o];
        #pragma unroll
        for (int rg = 0; rg < 4; ++rg) {
            float v = fmaxf(acc[rg] + bv, 0.f);
            sh[q * 4 + rg][o] = v;
        }
    }
    __syncthreads();

    #pragma unroll
    for (int e = 0; e < 8; ++e) {
        int lin = e * 256 + t;
        int rr = lin >> 7, cc = lin & 127;
        houtbf[(size_t)i0 * HH + lin] = f2bf(sh[rr][cc]);
    }
    int rep = blockIdx.x & (NREP - 1);
    if (t < HH) {
        float accq[NTYPES] = {0.f, 0.f, 0.f, 0.f, 0.f, 0.f};
        for (int r = 0; r < 16; ++r) {
            float v = sh[r][t];
            int tt = stypes[r];
            #pragma unroll
            for (int qq = 0; qq < NTYPES; ++qq)
                accq[qq] += (tt == qq) ? v : 0.f;
        }
        #pragma unroll
        for (int qq = 0; qq < NTYPES; ++qq)
            atomicAdd(&acc0[(rep * NTYPES + qq) * HH + t], accq[qq]);
    }
}

// ---------------------------------------------------------------------------
// Kernel M2F (layer-2 GEMM + BN finalize fused): 256 blocks <= 256 CUs, so
// all blocks are co-resident by capacity (even at 1 block/CU) — the counter
// handshake cannot deadlock. Blocks publish BN partials with device-scope
// atomics, arrive, spin until all 256 arrived, then normalize their 16 rows
// straight from LDS (h2 never touches global memory) and emit the head.
// ---------------------------------------------------------------------------
__global__ __launch_bounds__(256) void gemm_l2_final(
    const ushortT* __restrict__ mbf, const ushortT* __restrict__ hbf,
    const ushortT* __restrict__ Wlbf, const ushortT* __restrict__ Wrbf,
    const float* __restrict__ bl,
    float* __restrict__ musum, float* __restrict__ varsum,
    int* __restrict__ done,
    const float* __restrict__ gamma, const float* __restrict__ beta,
    const float* __restrict__ Wo, const float* __restrict__ bo,
    float* __restrict__ out_h, float* __restrict__ out_o)
{
    int t = threadIdx.x;
    int wv = t >> 6, lane = t & 63;
    int p = lane & 15, q = lane >> 4;
    int i0 = blockIdx.x * 16;

    __shared__ float sh[16][129];
    __shared__ float ssc[HH], ssh[HH];

    const ushortT* arow_m = mbf + (size_t)(i0 + p) * HH + q * 8;
    const ushortT* arow_h = hbf + (size_t)(i0 + p) * HH + q * 8;
    short8 am[4], ah[4];
    #pragma unroll
    for (int s = 0; s < 4; ++s) {
        am[s] = *(const short8*)(arow_m + s * 32);
        ah[s] = *(const short8*)(arow_h + s * 32);
    }

    #pragma unroll
    for (int nt = 0; nt < 2; ++nt) {
        int n0 = (wv * 2 + nt) * 16;
        const ushortT* brow_l = Wlbf + (size_t)(n0 + p) * HH + q * 8;
        const ushortT* brow_r = Wrbf + (size_t)(n0 + p) * HH + q * 8;
        f32x4 acc = {0.f, 0.f, 0.f, 0.f};
        #pragma unroll
        for (int s = 0; s < 4; ++s) {
            short8 b = *(const short8*)(brow_l + s * 32);
            acc = __builtin_amdgcn_mfma_f32_16x16x32_bf16(am[s], b, acc, 0, 0, 0);
        }
        #pragma unroll
        for (int s = 0; s < 4; ++s) {
            short8 b = *(const short8*)(brow_r + s * 32);
            acc = __builtin_amdgcn_mfma_f32_16x16x32_bf16(ah[s], b, acc, 0, 0, 0);
        }
        int o = n0 + p;
        float bv = bl[o];
        #pragma unroll
        for (int rg = 0; rg < 4; ++rg) {
            float v = fmaxf(acc[rg] + bv, 0.f);
            sh[q * 4 + rg][o] = v;
        }
    }
    __syncthreads();

    // BN partial stats (device-scope atomics)
    int rep = blockIdx.x & (NREP - 1);
    if (t < HH) {
        float s = 0.f, s2 = 0.f;
        for (int r = 0; r < 16; ++r) {
            float v = sh[r][t];
            s += v; s2 += v * v;
        }
        atomicAdd(&musum[rep * HH + t], s);
        atomicAdd(&varsum[rep * HH + t], s2);
    }
    __syncthreads();
    __threadfence();
    if (t == 0) {
        __hip_atomic_fetch_add(done, 1, __ATOMIC_ACQ_REL, __HIP_MEMORY_SCOPE_AGENT);
        while (__hip_atomic_load(done, __ATOMIC_ACQUIRE,
                                 __HIP_MEMORY_SCOPE_AGENT) < NN / 16) {
            __builtin_amdgcn_s_sleep(2);
        }
    }
    __syncthreads();

    // Global stats ready: fold replicas (agent-scope loads bypass stale L1/L2)
    if (t < HH) {
        float ms = 0.f, vs = 0.f;
        #pragma unroll
        for (int r = 0; r < NREP; ++r) {
            ms += __hip_atomic_load(&musum[r * HH + t], __ATOMIC_RELAXED,
                                    __HIP_MEMORY_SCOPE_AGENT);
            vs += __hip_atomic_load(&varsum[r * HH + t], __ATOMIC_RELAXED,
                                    __HIP_MEMORY_SCOPE_AGENT);
        }
        float mu = ms * (1.f / NN);
        float va = vs * (1.f / NN) - mu * mu;
        float sc = gamma[t] / sqrtf(va + BN_EPS);
        ssc[t] = sc;
        ssh[t] = beta[t] - mu * sc;
    }
    __syncthreads();

    // normalize + coalesced out_h write; stash normalized rows back in LDS
    #pragma unroll
    for (int e = 0; e < 8; ++e) {
        int lin = e * 256 + t;
        int rr = lin >> 7, cc = lin & 127;
        float v = sh[rr][cc] * ssc[cc] + ssh[cc];
        sh[rr][cc] = v;
        out_h[(size_t)i0 * HH + lin] = v;
    }
    __syncthreads();

    // head: wave wv handles rows 4*wv..4*wv+3
    float2 w0 = ((const float2*)Wo)[lane];
    float2 w1 = ((const float2*)(Wo + HH))[lane];
    float2 w2 = ((const float2*)(Wo + 2 * HH))[lane];
    #pragma unroll
    for (int rr = 0; rr < 4; ++rr) {
        int row = wv * 4 + rr;
        float a = sh[row][lane * 2];
        float b = sh[row][lane * 2 + 1];
        float p0 = a * w0.x + b * w0.y;
        float p1 = a * w1.x + b * w1.y;
        float p2 = a * w2.x + b * w2.y;
        for (int s = 32; s; s >>= 1) {
            p0 += __shfl_down(p0, s);
            p1 += __shfl_down(p1, s);
            p2 += __shfl_down(p2, s);
        }
        if (lane == 0) {
            out_o[(size_t)(i0 + row) * OUTD + 0] = p0 + bo[0];
            out_o[(size_t)(i0 + row) * OUTD + 1] = p1 + bo[1];
            out_o[(size_t)(i0 + row) * OUTD + 2] = p2 + bo[2];
        }
    }
}

// ---------------------------------------------------------------------------
extern "C" void kernel_launch(void* const* d_in, const int* in_sizes, int n_in,
                              void* d_out, int out_size, void* d_ws, size_t ws_size,
                              hipStream_t stream)
{
    (void)in_sizes; (void)n_in; (void)out_size; (void)ws_size;
    const float* x_now = (const float*)d_in[0];
    const int*   sat   = (const int*)d_in[1];
    const float* Wl    = (const float*)d_in[2];
    const float* bl    = (const float*)d_in[3];
    const float* Wr    = (const float*)d_in[4];
    const float* gamma = (const float*)d_in[5];
    const float* beta  = (const float*)d_in[6];
    const float* Wo    = (const float*)d_in[7];
    const float* bo    = (const float*)d_in[8];

    ushortT* Wbf  = (ushortT*)d_ws;               // 65536 us [Wl0,Wl1,Wr0,Wr1]
    ushortT* x0bf = Wbf + 65536;                  // 524288 us
    ushortT* h1bf = x0bf + (size_t)NN * HH;       // 524288 us
    ushortT* mbf  = h1bf + (size_t)NN * HH;       // 524288 us (both layers)
    float4* fn = (float4*)(mbf + (size_t)NN * HH);      // 4096 float4
    unsigned* mask = (unsigned*)((float*)fn + 4 * NN);  // 524288 words
    float* deg = (float*)(mask + (size_t)NN * 128);     // 4096
    // ---- zeroed accumulator region (one contiguous memset) ----
    int*   cnt   = (int*)(deg + NN);              // NREP*6 (reserve 64)
    float* S0rep = (float*)(cnt + 64);            // 6144
    float* S1rep = S0rep + NREP * NTYPES * HH;    // 6144
    float* mu8   = S1rep + NREP * NTYPES * HH;    // 1024
    float* var8  = mu8 + NREP * HH;               // 1024
    int*   done  = (int*)(var8 + NREP * HH);      // 1 (reserve 16)

    size_t zero_bytes = (64 + 2 * NREP * NTYPES * HH + 2 * NREP * HH + 16)
                        * sizeof(float);
    hipMemsetAsync(cnt, 0, zero_bytes, stream);

    prep<<<264, 256, 0, stream>>>(x_now, sat, Wl, Wr, Wbf, x0bf, fn, cnt,
                                  S0rep);
    // fused mask + layer-1 gather
    maskgather<<<NN / MROW, 256, 0, stream>>>(fn, sat, cnt, S0rep, x0bf,
                                              mask, deg, mbf);
    gemm_l1<<<NN / 16, 256, 0, stream>>>(mbf, x0bf, Wbf, Wbf + 32768, bl, sat,
                                         h1bf, S1rep);
    gather2<<<NN / 2, 256, 0, stream>>>(h1bf, mask, deg, S1rep, sat, mbf);
    gemm_l2_final<<<NN / 16, 256, 0, stream>>>(
        mbf, h1bf, Wbf + 16384, Wbf + 49152, bl + HH, mu8, var8, done,
        gamma, beta, Wo, bo, (float*)d_out, (float*)d_out + (size_t)NN * HH);
}

// Round 2
// 133.941 us; speedup vs baseline: 1.1333x; 1.1333x over previous
//
#include <hip/hip_runtime.h>
#include <math.h>

#define NN 4096
#define DD 127
#define HH 128
#define OUTD 3
#define NTYPES 6
#define SIM_THRESH 0.9f
#define BN_EPS 1e-5f
#define MROW 4    // rows per block in build_mask
#define NREP 8    // accumulator replicas
// Half-row neighbor list capacity. Half-degree ~ Binomial(1706, 0.05):
// mean 85, sigma 9 -> 256 = 19-sigma bound.
#define LMAXH 256

typedef unsigned short ushortT;
typedef __attribute__((ext_vector_type(8))) short short8;   // 8 bf16 (4 VGPRs)
typedef __attribute__((ext_vector_type(4))) float f32x4;

// round-to-nearest-even fp32 -> bf16 (bit pattern)
static __device__ inline ushortT f2bf(float f) {
    unsigned u = __float_as_uint(f);
    unsigned r = (u + 0x7fffu + ((u >> 16) & 1u)) >> 16;
    return (ushortT)r;
}
static __device__ inline float bflo(unsigned w) { return __uint_as_float(w << 16); }
static __device__ inline float bfhi(unsigned w) { return __uint_as_float(w & 0xffff0000u); }

#define BFACC(vv)                                                         \
    {                                                                     \
        acc[0] += __uint_as_float((vv).x << 16);                          \
        acc[1] += __uint_as_float((vv).x & 0xffff0000u);                  \
        acc[2] += __uint_as_float((vv).y << 16);                          \
        acc[3] += __uint_as_float((vv).y & 0xffff0000u);                  \
        acc[4] += __uint_as_float((vv).z << 16);                          \
        acc[5] += __uint_as_float((vv).z & 0xffff0000u);                  \
        acc[6] += __uint_as_float((vv).w << 16);                          \
        acc[7] += __uint_as_float((vv).w & 0xffff0000u);                  \
    }

// ---------------------------------------------------------------------------
// Kernel P: blocks 0..7 convert W (Wl0,Wl1,Wr0,Wr1) to bf16 row-major.
// Blocks 8..263: 16-row strips: xbf (bf16 only — fp32 x dropped; strip staged
// in LDS for the S0 sums), fn, type histogram, S0 type-sums (NREP replicas).
// ---------------------------------------------------------------------------
__global__ __launch_bounds__(256) void prep(
    const float* __restrict__ x_now, const int* __restrict__ sat,
    const float* __restrict__ Wl, const float* __restrict__ Wr,
    ushortT* __restrict__ Wbf, ushortT* __restrict__ xbf,
    float4* __restrict__ fn, int* __restrict__ cnt, float* __restrict__ S0rep)
{
    int t = threadIdx.x;
    if (blockIdx.x < 8) {
        int baseidx = blockIdx.x * 8192;
        #pragma unroll
        for (int it = 0; it < 32; ++it) {
            int idx = baseidx + it * 256 + t;
            float v = (idx < 32768) ? Wl[idx] : Wr[idx - 32768];
            Wbf[idx] = f2bf(v);
        }
        return;
    }

    int sb = blockIdx.x - 8;           // strip 0..255
    int base = sb * 16;
    int rep = sb & (NREP - 1);
    __shared__ int stypes[16];
    __shared__ float xs[16][HH];       // 8 KB strip stage
    int myti = -1;
    if (t < 16) {
        int row = base + t;
        int ti = sat[row]; ti = min(max(ti, 0), NTYPES - 1);
        stypes[t] = ti; myti = ti;
        const float* rp = x_now + (size_t)row * DD;
        float f0 = rp[0], f2 = rp[1], f3 = rp[2];
        float nrm = fmaxf(sqrtf(2.f * f0 * f0 + f2 * f2 + f3 * f3), 1e-12f);
        float inv = 1.f / nrm;
        fn[row] = make_float4(f0 * inv, f0 * inv, f2 * inv, f3 * inv);
    }
    #pragma unroll
    for (int it = 0; it < 8; ++it) {
        int lin = it * 256 + t;        // 0..2047
        int rl = lin >> 7, col = lin & 127;
        int row = base + rl;
        const float* rp = x_now + (size_t)row * DD;
        float v = (col == 0) ? rp[0] : rp[col - 1];
        xs[rl][col] = v;
        xbf[(size_t)row * HH + col] = f2bf(v);
    }
    __syncthreads();
    if (t < 64) {
        #pragma unroll
        for (int tt = 0; tt < NTYPES; ++tt) {
            unsigned long long m = __ballot(myti == tt);
            if (t == 0) {
                int c = __popcll(m);
                if (c) atomicAdd(&cnt[rep * NTYPES + tt], c);
            }
        }
    }
    if (t < 128) {
        float acc[NTYPES] = {0.f, 0.f, 0.f, 0.f, 0.f, 0.f};
        for (int r = 0; r < 16; ++r) {
            float v = xs[r][t];
            int tt = stypes[r];
            #pragma unroll
            for (int q = 0; q < NTYPES; ++q) acc[q] += (tt == q) ? v : 0.f;
        }
        #pragma unroll
        for (int q = 0; q < NTYPES; ++q)
            atomicAdd(&S0rep[(rep * NTYPES + q) * HH + t], acc[q]);
    }
}

// ---------------------------------------------------------------------------
// Kernel B (unchanged round-0 structure): bitmask + degree; b-loop split
// across two thread-halves.
// ---------------------------------------------------------------------------
__global__ __launch_bounds__(256) void build_mask(
    const float4* __restrict__ fn, const int* __restrict__ sat,
    const int* __restrict__ cnt, unsigned* __restrict__ mask,
    float* __restrict__ deg)
{
    int i0 = blockIdx.x * MROW;
    int t = threadIdx.x;
    int w = t & 127;
    int half = t >> 7;
    float4 fi[MROW];
    int ti[MROW];
    #pragma unroll
    for (int r = 0; r < MROW; ++r) {
        fi[r] = fn[i0 + r];
        int tt = sat[i0 + r];
        ti[r] = min(max(tt, 0), NTYPES - 1);
    }
    unsigned word[MROW] = {0, 0, 0, 0};
    int bbase = half * 16;
    for (int bb = 0; bb < 16; ++bb) {
        int b = bbase + bb;
        int j = b * 128 + w;
        float4 fj = fn[j];
        int tj = sat[j];
        #pragma unroll
        for (int r = 0; r < MROW; ++r) {
            float dot = fi[r].x * fj.x + fi[r].y * fj.y
                      + fi[r].z * fj.z + fi[r].w * fj.w;
            if (tj != ti[r] && dot > SIM_THRESH) word[r] |= (1u << b);
        }
    }
    __shared__ unsigned wpart[MROW][128];
    if (half == 1) {
        #pragma unroll
        for (int r = 0; r < MROW; ++r) wpart[r][w] = word[r];
    }
    __syncthreads();
    __shared__ int wt[2][MROW];
    if (half == 0) {
        int pcs[MROW];
        #pragma unroll
        for (int r = 0; r < MROW; ++r) {
            unsigned full = word[r] | wpart[r][w];
            mask[(size_t)(i0 + r) * 128 + w] = full;
            pcs[r] = __popc(full);
        }
        int lane = w & 63, wv2 = w >> 6;
        for (int s = 32; s; s >>= 1) {
            #pragma unroll
            for (int r = 0; r < MROW; ++r) pcs[r] += __shfl_down(pcs[r], s);
        }
        if (lane == 0) {
            #pragma unroll
            for (int r = 0; r < MROW; ++r) wt[wv2][r] = pcs[r];
        }
    }
    __syncthreads();
    if (t < MROW) {
        int r = t;
        int ctot = 0;
        #pragma unroll
        for (int rr = 0; rr < NREP; ++rr) ctot += cnt[rr * NTYPES + ti[r]];
        float d = (float)(ctot - 1 + wt[0][r] + wt[1][r]);
        deg[i0 + r] = fmaxf(d, 1.0f);
    }
}

// ---------------------------------------------------------------------------
// Kernel G (gather-only, round-0 structure): two waves per row, bf16 gather;
// writes m as bf16. Only change vs round-0: the fp32 self-row stage (hs) is
// gone — self term read directly from the bf16 array in the epilogue
// (error ~ulp/deg ~1e-5, invisible at the test tolerance).
// ---------------------------------------------------------------------------
__global__ __launch_bounds__(256, 8) void gather_kernel(
    const ushortT* __restrict__ hbf, const unsigned* __restrict__ mask,
    const float* __restrict__ deg, const float* __restrict__ S,
    const int* __restrict__ sat, ushortT* __restrict__ mbf)
{
    int t = threadIdx.x;
    int wv = t >> 6;          // wave id 0..3
    int lane = t & 63;
    int r  = wv >> 1;         // row slot 0..1
    int hf = wv & 1;          // half 0..1
    int i0 = blockIdx.x * 2;
    int i = i0 + r;

    __shared__ ushortT list[4][LMAXH];                   // 2 KB
    __shared__ __align__(16) float part[4][HH];          // 2 KB
    __shared__ int tarr[2];

    if (t < 2) {
        int tt = sat[i0 + t];
        tarr[t] = min(max(tt, 0), NTYPES - 1);
    }

    // ---- decode: wave (r,hf) owns mask words hf*64+lane of row i ----
    int widx = hf * 64 + lane;
    unsigned word = mask[(size_t)i * 128 + widx];
    int pc = __popc(word);
    int x = pc;
    for (int s = 1; s < 64; s <<= 1) {
        int v = __shfl_up(x, s);
        if (lane >= s) x += v;
    }
    int ncnt = __shfl(x, 63);
    int ofs = x - pc;
    unsigned ww = word;
    while (ww) {
        int b = __ffs(ww) - 1; ww &= ww - 1;
        list[wv][ofs++] = (ushortT)(b * 128 + widx);
    }

    // ---- gather own half-list from bf16 rows: 4 rows/instr, 6 deep ----
    int q = lane >> 4;        // 0..3 neighbor slot
    int c = lane & 15;        // 0..15 -> columns 8c..8c+7
    const uint4* __restrict__ hb4 = (const uint4*)hbf;
    float acc[8] = {0.f, 0.f, 0.f, 0.f, 0.f, 0.f, 0.f, 0.f};
    int g = 0;
    for (; g + 24 <= ncnt; g += 24) {
        int j0 = list[wv][g + q];
        int j1 = list[wv][g + 4 + q];
        int j2 = list[wv][g + 8 + q];
        int j3 = list[wv][g + 12 + q];
        int j4 = list[wv][g + 16 + q];
        int j5 = list[wv][g + 20 + q];
        uint4 v0 = hb4[j0 * 16 + c];
        uint4 v1 = hb4[j1 * 16 + c];
        uint4 v2 = hb4[j2 * 16 + c];
        uint4 v3 = hb4[j3 * 16 + c];
        uint4 v4 = hb4[j4 * 16 + c];
        uint4 v5 = hb4[j5 * 16 + c];
        BFACC(v0); BFACC(v1); BFACC(v2); BFACC(v3); BFACC(v4); BFACC(v5);
    }
    for (; g + 4 <= ncnt; g += 4) {
        int j0 = list[wv][g + q];
        uint4 v0 = hb4[j0 * 16 + c];
        BFACC(v0);
    }
    if (q < ncnt - g) {
        int j0 = list[wv][g + q];
        uint4 v0 = hb4[j0 * 16 + c];
        BFACC(v0);
    }
    #pragma unroll
    for (int d = 0; d < 8; ++d) {
        acc[d] += __shfl_down(acc[d], 32);
        acc[d] += __shfl_down(acc[d], 16);
    }
    if (lane < 16) {
        float4 p0 = {acc[0], acc[1], acc[2], acc[3]};
        float4 p1 = {acc[4], acc[5], acc[6], acc[7]};
        ((float4*)part[wv])[c * 2] = p0;
        ((float4*)part[wv])[c * 2 + 1] = p1;
    }
    __syncthreads();   // partials + tarr ready

    if (hf == 0 && lane < 32) {
        int cc = lane;
        float4 p0 = ((const float4*)part[wv])[cc];
        float4 p1 = ((const float4*)part[wv + 1])[cc];
        int ti = tarr[r];
        float rdeg = 1.f / deg[i];
        uint2 hw = ((const uint2*)(hbf + (size_t)i * HH))[cc];
        float4 hv = {bflo(hw.x), bfhi(hw.x), bflo(hw.y), bfhi(hw.y)};
        float4 Sv = {0.f, 0.f, 0.f, 0.f};
        #pragma unroll
        for (int rr = 0; rr < NREP; ++rr) {
            float4 sv = ((const float4*)S)[(rr * NTYPES + ti) * 32 + cc];
            Sv.x += sv.x; Sv.y += sv.y; Sv.z += sv.z; Sv.w += sv.w;
        }
        float4 m;
        m.x = (Sv.x - hv.x + p0.x + p1.x) * rdeg;
        m.y = (Sv.y - hv.y + p0.y + p1.y) * rdeg;
        m.z = (Sv.z - hv.z + p0.z + p1.z) * rdeg;
        m.w = (Sv.w - hv.w + p0.w + p1.w) * rdeg;
        ushort4 mb;
        mb.x = f2bf(m.x); mb.y = f2bf(m.y);
        mb.z = f2bf(m.z); mb.w = f2bf(m.w);
        ((ushort4*)(mbf + (size_t)i * HH))[cc] = mb;
    }
}

// ---------------------------------------------------------------------------
// Kernel M1 (layer-1 MFMA GEMM): h1 = relu([mbf | xbf] @ [Wl0 | Wr0]^T + bl0).
// Writes bf16 h1 only (fp32 h1 dropped) + next-layer type sums.
// ---------------------------------------------------------------------------
__global__ __launch_bounds__(256) void gemm_l1(
    const ushortT* __restrict__ mbf, const ushortT* __restrict__ hbf,
    const ushortT* __restrict__ Wlbf, const ushortT* __restrict__ Wrbf,
    const float* __restrict__ bl, const int* __restrict__ sat,
    ushortT* __restrict__ houtbf, float* __restrict__ acc0)
{
    int t = threadIdx.x;
    int wv = t >> 6, lane = t & 63;
    int p = lane & 15, q = lane >> 4;
    int i0 = blockIdx.x * 16;

    __shared__ float sh[16][129];
    __shared__ int stypes[16];
    if (t < 16) {
        int tt = sat[i0 + t];
        stypes[t] = min(max(tt, 0), NTYPES - 1);
    }

    // A fragments: row i0+p, k = s*32 + q*8 .. +7 (k-contiguous per lane)
    const ushortT* arow_m = mbf + (size_t)(i0 + p) * HH + q * 8;
    const ushortT* arow_h = hbf + (size_t)(i0 + p) * HH + q * 8;
    short8 am[4], ah[4];
    #pragma unroll
    for (int s = 0; s < 4; ++s) {
        am[s] = *(const short8*)(arow_m + s * 32);
        ah[s] = *(const short8*)(arow_h + s * 32);
    }

    #pragma unroll
    for (int nt = 0; nt < 2; ++nt) {
        int n0 = (wv * 2 + nt) * 16;
        const ushortT* brow_l = Wlbf + (size_t)(n0 + p) * HH + q * 8;
        const ushortT* brow_r = Wrbf + (size_t)(n0 + p) * HH + q * 8;
        f32x4 acc = {0.f, 0.f, 0.f, 0.f};
        #pragma unroll
        for (int s = 0; s < 4; ++s) {
            short8 b = *(const short8*)(brow_l + s * 32);
            acc = __builtin_amdgcn_mfma_f32_16x16x32_bf16(am[s], b, acc, 0, 0, 0);
        }
        #pragma unroll
        for (int s = 0; s < 4; ++s) {
            short8 b = *(const short8*)(brow_r + s * 32);
            acc = __builtin_amdgcn_mfma_f32_16x16x32_bf16(ah[s], b, acc, 0, 0, 0);
        }
        int o = n0 + p;              // D col = lane&15
        float bv = bl[o];
        #pragma unroll
        for (int rg = 0; rg < 4; ++rg) {
            float v = fmaxf(acc[rg] + bv, 0.f);
            sh[q * 4 + rg][o] = v;   // D row = quad*4 + reg
        }
    }
    __syncthreads();

    #pragma unroll
    for (int e = 0; e < 8; ++e) {
        int lin = e * 256 + t;
        int rr = lin >> 7, cc = lin & 127;
        houtbf[(size_t)i0 * HH + lin] = f2bf(sh[rr][cc]);
    }
    int rep = blockIdx.x & (NREP - 1);
    if (t < HH) {
        float accq[NTYPES] = {0.f, 0.f, 0.f, 0.f, 0.f, 0.f};
        for (int r = 0; r < 16; ++r) {
            float v = sh[r][t];
            int tt = stypes[r];
            #pragma unroll
            for (int qq = 0; qq < NTYPES; ++qq)
                accq[qq] += (tt == qq) ? v : 0.f;
        }
        #pragma unroll
        for (int qq = 0; qq < NTYPES; ++qq)
            atomicAdd(&acc0[(rep * NTYPES + qq) * HH + t], accq[qq]);
    }
}

// ---------------------------------------------------------------------------
// Kernel M2 (layer-2 MFMA GEMM, round-0 MODE 2): writes fp32 h2 + BN stat
// replicas. No grid handshake (that was a round-1 regressor).
// ---------------------------------------------------------------------------
__global__ __launch_bounds__(256) void gemm_l2(
    const ushortT* __restrict__ mbf, const ushortT* __restrict__ hbf,
    const ushortT* __restrict__ Wlbf, const ushortT* __restrict__ Wrbf,
    const float* __restrict__ bl, float* __restrict__ hout,
    float* __restrict__ acc0, float* __restrict__ acc1)
{
    int t = threadIdx.x;
    int wv = t >> 6, lane = t & 63;
    int p = lane & 15, q = lane >> 4;
    int i0 = blockIdx.x * 16;

    __shared__ float sh[16][129];

    const ushortT* arow_m = mbf + (size_t)(i0 + p) * HH + q * 8;
    const ushortT* arow_h = hbf + (size_t)(i0 + p) * HH + q * 8;
    short8 am[4], ah[4];
    #pragma unroll
    for (int s = 0; s < 4; ++s) {
        am[s] = *(const short8*)(arow_m + s * 32);
        ah[s] = *(const short8*)(arow_h + s * 32);
    }

    #pragma unroll
    for (int nt = 0; nt < 2; ++nt) {
        int n0 = (wv * 2 + nt) * 16;
        const ushortT* brow_l = Wlbf + (size_t)(n0 + p) * HH + q * 8;
        const ushortT* brow_r = Wrbf + (size_t)(n0 + p) * HH + q * 8;
        f32x4 acc = {0.f, 0.f, 0.f, 0.f};
        #pragma unroll
        for (int s = 0; s < 4; ++s) {
            short8 b = *(const short8*)(brow_l + s * 32);
            acc = __builtin_amdgcn_mfma_f32_16x16x32_bf16(am[s], b, acc, 0, 0, 0);
        }
        #pragma unroll
        for (int s = 0; s < 4; ++s) {
            short8 b = *(const short8*)(brow_r + s * 32);
            acc = __builtin_amdgcn_mfma_f32_16x16x32_bf16(ah[s], b, acc, 0, 0, 0);
        }
        int o = n0 + p;
        float bv = bl[o];
        #pragma unroll
        for (int rg = 0; rg < 4; ++rg) {
            float v = fmaxf(acc[rg] + bv, 0.f);
            sh[q * 4 + rg][o] = v;
        }
    }
    __syncthreads();

    #pragma unroll
    for (int e = 0; e < 8; ++e) {
        int lin = e * 256 + t;
        int rr = lin >> 7, cc = lin & 127;
        hout[(size_t)i0 * HH + lin] = sh[rr][cc];
    }
    int rep = blockIdx.x & (NREP - 1);
    if (t < HH) {
        float s = 0.f, s2 = 0.f;
        for (int r = 0; r < 16; ++r) {
            float v = sh[r][t];
            s += v; s2 += v * v;
        }
        atomicAdd(&acc0[rep * HH + t], s);
        atomicAdd(&acc1[rep * HH + t], s2);
    }
}

// ---------------------------------------------------------------------------
// Kernel F: BN apply + head, one wave per row; sums the NREP stat replicas.
// (exact round-0 version)
// ---------------------------------------------------------------------------
__global__ __launch_bounds__(256) void finalize(
    const float* __restrict__ h, const float* __restrict__ musum8,
    const float* __restrict__ varsum8, const float* __restrict__ gamma,
    const float* __restrict__ beta, const float* __restrict__ Wo,
    const float* __restrict__ bo, float* __restrict__ out_h,
    float* __restrict__ out_o)
{
    int t = threadIdx.x;
    int wv = t >> 6;
    int lane = t & 63;
    int i = blockIdx.x * 4 + wv;

    float2 mus = {0.f, 0.f}, vas = {0.f, 0.f};
    #pragma unroll
    for (int r = 0; r < NREP; ++r) {
        float2 a = ((const float2*)(musum8 + r * HH))[lane];
        float2 b = ((const float2*)(varsum8 + r * HH))[lane];
        mus.x += a.x; mus.y += a.y;
        vas.x += b.x; vas.y += b.y;
    }
    float2 ga  = ((const float2*)gamma)[lane];
    float2 be  = ((const float2*)beta)[lane];
    float mu0 = mus.x * (1.f / NN), mu1 = mus.y * (1.f / NN);
    float v0 = vas.x * (1.f / NN) - mu0 * mu0;
    float v1 = vas.y * (1.f / NN) - mu1 * mu1;
    float sc0 = ga.x / sqrtf(v0 + BN_EPS), sc1 = ga.y / sqrtf(v1 + BN_EPS);
    float sh0 = be.x - mu0 * sc0, sh1 = be.y - mu1 * sc1;

    float2 hv = ((const float2*)(h + (size_t)i * HH))[lane];
    float2 hb;
    hb.x = hv.x * sc0 + sh0;
    hb.y = hv.y * sc1 + sh1;
    ((float2*)(out_h + (size_t)i * HH))[lane] = hb;

    float2 w0 = ((const float2*)Wo)[lane];
    float2 w1 = ((const float2*)(Wo + HH))[lane];
    float2 w2 = ((const float2*)(Wo + 2 * HH))[lane];
    float p0 = hb.x * w0.x + hb.y * w0.y;
    float p1 = hb.x * w1.x + hb.y * w1.y;
    float p2 = hb.x * w2.x + hb.y * w2.y;
    for (int s = 32; s; s >>= 1) {
        p0 += __shfl_down(p0, s);
        p1 += __shfl_down(p1, s);
        p2 += __shfl_down(p2, s);
    }
    if (lane == 0) {
        out_o[(size_t)i * OUTD + 0] = p0 + bo[0];
        out_o[(size_t)i * OUTD + 1] = p1 + bo[1];
        out_o[(size_t)i * OUTD + 2] = p2 + bo[2];
    }
}

// ---------------------------------------------------------------------------
extern "C" void kernel_launch(void* const* d_in, const int* in_sizes, int n_in,
                              void* d_out, int out_size, void* d_ws, size_t ws_size,
                              hipStream_t stream)
{
    (void)in_sizes; (void)n_in; (void)out_size; (void)ws_size;
    const float* x_now = (const float*)d_in[0];
    const int*   sat   = (const int*)d_in[1];
    const float* Wl    = (const float*)d_in[2];
    const float* bl    = (const float*)d_in[3];
    const float* Wr    = (const float*)d_in[4];
    const float* gamma = (const float*)d_in[5];
    const float* beta  = (const float*)d_in[6];
    const float* Wo    = (const float*)d_in[7];
    const float* bo    = (const float*)d_in[8];

    ushortT* Wbf  = (ushortT*)d_ws;               // 65536 us [Wl0,Wl1,Wr0,Wr1]
    ushortT* x0bf = Wbf + 65536;                  // 524288 us
    ushortT* h1bf = x0bf + (size_t)NN * HH;       // 524288 us
    ushortT* mbf  = h1bf + (size_t)NN * HH;       // 524288 us (both layers)
    float* h2 = (float*)(mbf + (size_t)NN * HH);  // 524288 f
    float4* fn = (float4*)(h2 + (size_t)NN * HH);       // 4096 float4
    unsigned* mask = (unsigned*)((float*)fn + 4 * NN);  // 524288 words
    float* deg = (float*)(mask + (size_t)NN * 128);     // 4096
    // ---- zeroed accumulator region (one contiguous memset) ----
    int*   cnt   = (int*)(deg + NN);              // NREP*6 (reserve 64)
    float* S0rep = (float*)(cnt + 64);            // 6144
    float* S1rep = S0rep + NREP * NTYPES * HH;    // 6144
    float* mu8   = S1rep + NREP * NTYPES * HH;    // 1024
    float* var8  = mu8 + NREP * HH;               // 1024

    size_t zero_bytes = (64 + 2 * NREP * NTYPES * HH + 2 * NREP * HH)
                        * sizeof(float);
    hipMemsetAsync(cnt, 0, zero_bytes, stream);

    prep<<<264, 256, 0, stream>>>(x_now, sat, Wl, Wr, Wbf, x0bf, fn, cnt,
                                  S0rep);
    build_mask<<<NN / MROW, 256, 0, stream>>>(fn, sat, cnt, mask, deg);

    // layer 1
    gather_kernel<<<NN / 2, 256, 0, stream>>>(x0bf, mask, deg, S0rep, sat,
                                              mbf);
    gemm_l1<<<NN / 16, 256, 0, stream>>>(mbf, x0bf, Wbf, Wbf + 32768, bl, sat,
                                         h1bf, S1rep);

    // layer 2
    gather_kernel<<<NN / 2, 256, 0, stream>>>(h1bf, mask, deg, S1rep, sat,
                                              mbf);
    gemm_l2<<<NN / 16, 256, 0, stream>>>(mbf, h1bf, Wbf + 16384, Wbf + 49152,
                                         bl + HH, h2, mu8, var8);

    finalize<<<NN / 4, 256, 0, stream>>>(h2, mu8, var8, gamma, beta, Wo, bo,
                                         (float*)d_out, (float*)d_out + (size_t)NN * HH);
}